// Round 4
// baseline (4479.470 us; speedup 1.0000x reference)
//
#include <hip/hip_runtime.h>
#include <hip/hip_bf16.h>

// ---- types ----
typedef __bf16 bf16_t;
typedef bf16_t bf16x8 __attribute__((ext_vector_type(8)));
typedef float  f32x4  __attribute__((ext_vector_type(4)));

#define T_TOK 2048
#define DM    2048
#define D3    6144
#define NHEAD 16
#define HDIM  128

// ------------------------------------------------------------------
// load 8 contiguous elements as bf16x8; f32 flag selects fp32->bf16 convert
// ------------------------------------------------------------------
__device__ inline bf16x8 ld8_cvt(const float* p) {
  const float4 a = *(const float4*)p, b = *(const float4*)(p + 4);
  bf16x8 o;
  o[0] = (bf16_t)a.x; o[1] = (bf16_t)a.y; o[2] = (bf16_t)a.z; o[3] = (bf16_t)a.w;
  o[4] = (bf16_t)b.x; o[5] = (bf16_t)b.y; o[6] = (bf16_t)b.z; o[7] = (bf16_t)b.w;
  return o;
}
__device__ inline bf16x8 ld8(const void* base, long off, int f32) {
  if (f32) return ld8_cvt((const float*)base + off);
  return *(const bf16x8*)((const bf16_t*)base + off);
}

// ------------------------------------------------------------------
// block reduction: sum of (a,b) across 256 threads, result to all
// ------------------------------------------------------------------
__device__ inline float2 block_reduce2(float a, float b, float* sm) {
  #pragma unroll
  for (int off = 32; off > 0; off >>= 1) {
    a += __shfl_down(a, off);
    b += __shfl_down(b, off);
  }
  const int lane = threadIdx.x & 63, w = threadIdx.x >> 6;
  __syncthreads();
  if (lane == 0) { sm[w] = a; sm[8 + w] = b; }
  __syncthreads();
  float2 r;
  r.x = sm[0] + sm[1] + sm[2] + sm[3];
  r.y = sm[8] + sm[9] + sm[10] + sm[11];
  return r;
}

// ------------------------------------------------------------------
// GEMM: C = X[M,K] @ W[N,K]^T, bf16 MFMA, fp32 acc. xf32/wf32 select fp32
// inputs (converted during LDS staging); cf32 selects fp32 output.
// Optional clip [-8,8]. 128x128 tile, BK=32. (m91-m93 verified pattern)
// ------------------------------------------------------------------
__global__ __launch_bounds__(256) void gemm_bt_kernel(
    const void* __restrict__ Xv, const void* __restrict__ Wv,
    void* __restrict__ Cv,
    int M, int N, int K, int xf32, int wf32, int cf32, int do_clip)
{
  __shared__ bf16_t As[128 * 40];   // 80B stride: 16B-aligned, 2-way alias only
  __shared__ bf16_t Bs[128 * 40];

  const int tx   = threadIdx.x;
  const int wave = tx >> 6, lane = tx & 63;
  const int qd   = lane >> 4, ln = lane & 15;
  const int m0 = blockIdx.y * 128, n0 = blockIdx.x * 128;
  const int row = tx >> 2, cg = (tx & 3) * 8;

  const long xoa = (long)(m0 + row)      * K + cg;
  const long xob = (long)(m0 + row + 64) * K + cg;
  const long woa = (long)(n0 + row)      * K + cg;
  const long wob = (long)(n0 + row + 64) * K + cg;

  const int wrow = (wave & 1) * 64, wcol = (wave >> 1) * 64;
  f32x4 acc[4][4] = {};

  for (int k0 = 0; k0 < K; k0 += 32) {
    __syncthreads();
    *(bf16x8*)&As[row * 40 + cg]        = ld8(Xv, xoa + k0, xf32);
    *(bf16x8*)&As[(row + 64) * 40 + cg] = ld8(Xv, xob + k0, xf32);
    *(bf16x8*)&Bs[row * 40 + cg]        = ld8(Wv, woa + k0, wf32);
    *(bf16x8*)&Bs[(row + 64) * 40 + cg] = ld8(Wv, wob + k0, wf32);
    __syncthreads();

    bf16x8 af[4], bfr[4];
    #pragma unroll
    for (int mi = 0; mi < 4; ++mi)
      af[mi] = *(const bf16x8*)&As[(wrow + mi * 16 + ln) * 40 + qd * 8];
    #pragma unroll
    for (int ni = 0; ni < 4; ++ni)
      bfr[ni] = *(const bf16x8*)&Bs[(wcol + ni * 16 + ln) * 40 + qd * 8];
    #pragma unroll
    for (int mi = 0; mi < 4; ++mi)
      #pragma unroll
      for (int ni = 0; ni < 4; ++ni)
        acc[mi][ni] = __builtin_amdgcn_mfma_f32_16x16x32_bf16(
            af[mi], bfr[ni], acc[mi][ni], 0, 0, 0);
  }

  // C/D layout: col = lane&15, row = quad*4 + reg  [learn_hip m89/m91]
  #pragma unroll
  for (int mi = 0; mi < 4; ++mi) {
    const int r0 = m0 + wrow + mi * 16 + qd * 4;
    #pragma unroll
    for (int ni = 0; ni < 4; ++ni) {
      const int c = n0 + wcol + ni * 16 + ln;
      #pragma unroll
      for (int r = 0; r < 4; ++r) {
        float v = acc[mi][ni][r];
        if (do_clip) v = fminf(fmaxf(v, -8.0f), 8.0f);
        if (cf32) ((float*)Cv)[(long)(r0 + r) * N + c] = v;
        else      ((bf16_t*)Cv)[(long)(r0 + r) * N + c] = (bf16_t)v;
      }
    }
  }
}

// ------------------------------------------------------------------
// Per-token: in-place LN(q), LN(k) inside bf16 qkv; cache gather
// (fp32 caches -> bf16 k_fin/v_fin). 1 block per token.
// ------------------------------------------------------------------
__global__ __launch_bounds__(256) void ln_gather_kernel(
    bf16_t* __restrict__ qkv,
    const float* __restrict__ qlw, const float* __restrict__ qlb,
    const float* __restrict__ klw, const float* __restrict__ klb,
    const float* __restrict__ k_cache, const float* __restrict__ v_cache,
    const int* __restrict__ cache_idx,
    bf16_t* __restrict__ k_fin, bf16_t* __restrict__ v_fin)
{
  const int t  = blockIdx.x;
  const int tx = threadIdx.x;
  const int o8 = tx * 8;
  __shared__ float sm[16];
  bf16_t* rowq = qkv + (long)t * D3;

  // ---- q LN (in place) ----
  {
    bf16x8 xv = *(const bf16x8*)(rowq + o8);
    float xf[8]; float s = 0.f, ss = 0.f;
    #pragma unroll
    for (int j = 0; j < 8; ++j) { xf[j] = (float)xv[j]; s += xf[j]; ss += xf[j] * xf[j]; }
    float2 red = block_reduce2(s, ss, sm);
    const float mean = red.x * (1.0f / DM);
    const float var  = red.y * (1.0f / DM) - mean * mean;
    const float rstd = rsqrtf(var + 1e-5f);
    const float4 w0 = *(const float4*)(qlw + o8), w1 = *(const float4*)(qlw + o8 + 4);
    const float4 b0 = *(const float4*)(qlb + o8), b1 = *(const float4*)(qlb + o8 + 4);
    const float wf[8] = {w0.x,w0.y,w0.z,w0.w,w1.x,w1.y,w1.z,w1.w};
    const float bb[8] = {b0.x,b0.y,b0.z,b0.w,b1.x,b1.y,b1.z,b1.w};
    bf16x8 y;
    #pragma unroll
    for (int j = 0; j < 8; ++j)
      y[j] = (bf16_t)((xf[j] - mean) * rstd * wf[j] + bb[j]);
    *(bf16x8*)(rowq + o8) = y;
  }

  // ---- k LN (in place) ----
  bf16x8 ky;
  {
    bf16x8 xv = *(const bf16x8*)(rowq + DM + o8);
    float xf[8]; float s = 0.f, ss = 0.f;
    #pragma unroll
    for (int j = 0; j < 8; ++j) { xf[j] = (float)xv[j]; s += xf[j]; ss += xf[j] * xf[j]; }
    float2 red = block_reduce2(s, ss, sm);
    const float mean = red.x * (1.0f / DM);
    const float var  = red.y * (1.0f / DM) - mean * mean;
    const float rstd = rsqrtf(var + 1e-5f);
    const float4 w0 = *(const float4*)(klw + o8), w1 = *(const float4*)(klw + o8 + 4);
    const float4 b0 = *(const float4*)(klb + o8), b1 = *(const float4*)(klb + o8 + 4);
    const float wf[8] = {w0.x,w0.y,w0.z,w0.w,w1.x,w1.y,w1.z,w1.w};
    const float bb[8] = {b0.x,b0.y,b0.z,b0.w,b1.x,b1.y,b1.z,b1.w};
    #pragma unroll
    for (int j = 0; j < 8; ++j)
      ky[j] = (bf16_t)((xf[j] - mean) * rstd * wf[j] + bb[j]);
    *(bf16x8*)(rowq + DM + o8) = ky;
  }

  // ---- gather (caches are fp32) ----
  const int ci = cache_idx[t];
  bf16x8 kf, vf;
  if (ci >= 0) {
    kf = ld8_cvt(k_cache + (long)ci * DM + o8);
    vf = ld8_cvt(v_cache + (long)ci * DM + o8);
  } else {
    kf = ky;
    vf = *(const bf16x8*)(rowq + 2 * DM + o8);
  }
  *(bf16x8*)(k_fin + (long)t * DM + o8) = kf;
  *(bf16x8*)(v_fin + (long)t * DM + o8) = vf;
}

// ------------------------------------------------------------------
// Sk alpha blend. 1 block per Sk entry (unique indices -> race free).
// ------------------------------------------------------------------
__global__ __launch_bounds__(256) void sk_blend_kernel(
    const int* __restrict__ Sk, const int* __restrict__ cache_idx,
    const float* __restrict__ k_cache, const float* __restrict__ v_cache,
    const bf16_t* __restrict__ qkv,
    bf16_t* __restrict__ k_fin, bf16_t* __restrict__ v_fin)
{
  const int t   = Sk[blockIdx.x];
  const int ci  = cache_idx[t];
  const int idx = ci < 0 ? 0 : ci;   // reference: clip(idx,0) even when <0
  const int o8  = threadIdx.x * 8;
  __shared__ float sm[16];

  const float* kr = k_cache + (long)idx * DM + o8;
  const float4 a0 = *(const float4*)kr, a1 = *(const float4*)(kr + 4);
  const float krf[8] = {a0.x,a0.y,a0.z,a0.w,a1.x,a1.y,a1.z,a1.w};
  bf16x8 kcv = *(const bf16x8*)(qkv + (long)t * D3 + DM + o8);
  float kcf[8]; float num = 0.f, den = 0.f;
  #pragma unroll
  for (int j = 0; j < 8; ++j) {
    kcf[j] = (float)kcv[j];
    const float d = kcf[j] - krf[j];
    num += d * d; den += krf[j] * krf[j];
  }
  float2 red = block_reduce2(num, den, sm);
  float alpha = red.x / fmaxf(red.y, 1e-6f);
  alpha = fminf(fmaxf(alpha, 0.0f), 1.0f);
  const float beta = 1.0f - alpha;

  bf16x8 ko;
  #pragma unroll
  for (int j = 0; j < 8; ++j) ko[j] = (bf16_t)(alpha * kcf[j] + beta * krf[j]);
  *(bf16x8*)(k_fin + (long)t * DM + o8) = ko;

  const float* vr = v_cache + (long)idx * DM + o8;
  const float4 c0 = *(const float4*)vr, c1 = *(const float4*)(vr + 4);
  const float vrf[8] = {c0.x,c0.y,c0.z,c0.w,c1.x,c1.y,c1.z,c1.w};
  bf16x8 vcv = *(const bf16x8*)(qkv + (long)t * D3 + 2 * DM + o8);
  bf16x8 vo;
  #pragma unroll
  for (int j = 0; j < 8; ++j)
    vo[j] = (bf16_t)(alpha * (float)vcv[j] + beta * vrf[j]);
  *(bf16x8*)(v_fin + (long)t * DM + o8) = vo;
}

// ------------------------------------------------------------------
// BISECTION attention: straightforward fp32 vector attention.
// One block per (token i, head h). Two-pass softmax with per-thread
// score registers (<=8 each), P in LDS, d-parallel PV. No MFMA.
// ------------------------------------------------------------------
__global__ __launch_bounds__(256) void attn_ref_kernel(
    const bf16_t* __restrict__ Q,   // stride D3 (q slice of qkv)
    const bf16_t* __restrict__ Kf,  // stride DM
    const bf16_t* __restrict__ Vf,  // stride DM
    bf16_t* __restrict__ O)         // stride DM
{
  const int i  = blockIdx.x;
  const int h  = blockIdx.y;
  const int tx = threadIdx.x;

  __shared__ float qs[HDIM];
  __shared__ float ps[T_TOK];
  __shared__ float redm[4], redl[4];
  __shared__ float oparts[256];

  if (tx < 16) {
    bf16x8 qv = *(const bf16x8*)&Q[(long)i * D3 + h * HDIM + tx * 8];
    #pragma unroll
    for (int u = 0; u < 8; ++u) qs[tx * 8 + u] = (float)qv[u];
  }
  __syncthreads();

  const float scale = 0.08838834764831845f;          // 1/sqrt(128)
  const float slope = exp2f(-0.5f * (float)(h + 1)); // alibi, H == npow

  // ---- pass 1: scores for this thread's keys (j = tx, tx+256, ...) ----
  float s_loc[8];
  float mt = -1e30f;
  int cnt = 0;
  for (int j = tx; j <= i; j += 256) {
    const bf16_t* krow = &Kf[(long)j * DM + h * HDIM];
    float s = 0.f;
    #pragma unroll
    for (int g = 0; g < 16; ++g) {
      bf16x8 kv = *(const bf16x8*)(krow + g * 8);
      #pragma unroll
      for (int u = 0; u < 8; ++u) s += qs[g * 8 + u] * (float)kv[u];
    }
    s = s * scale + slope * (float)(j - i);
    s_loc[cnt++] = s;
    mt = fmaxf(mt, s);
  }

  // ---- block max ----
  #pragma unroll
  for (int off = 32; off > 0; off >>= 1) mt = fmaxf(mt, __shfl_down(mt, off));
  if ((tx & 63) == 0) redm[tx >> 6] = mt;
  __syncthreads();
  const float m = fmaxf(fmaxf(redm[0], redm[1]), fmaxf(redm[2], redm[3]));

  // ---- p = exp(s-m) into LDS; partial l ----
  float lt = 0.f;
  cnt = 0;
  for (int j = tx; j <= i; j += 256) {
    const float p = __expf(s_loc[cnt++] - m);
    ps[j] = p;
    lt += p;
  }
  #pragma unroll
  for (int off = 32; off > 0; off >>= 1) lt += __shfl_down(lt, off);
  if ((tx & 63) == 0) redl[tx >> 6] = lt;
  __syncthreads();   // also makes ps[] visible to all
  const float l = redl[0] + redl[1] + redl[2] + redl[3];

  // ---- PV: thread handles dim d = tx&127, parity half = tx>>7 ----
  const int d = tx & 127, half = tx >> 7;
  float acc = 0.f;
  for (int j = half; j <= i; j += 2)
    acc += ps[j] * (float)Vf[(long)j * DM + h * HDIM + d];
  oparts[tx] = acc;
  __syncthreads();
  if (tx < 128)
    O[(long)i * DM + h * HDIM + tx] = (bf16_t)((oparts[tx] + oparts[tx + 128]) / l);
}

// ------------------------------------------------------------------
extern "C" void kernel_launch(void* const* d_in, const int* in_sizes, int n_in,
                              void* d_out, int out_size, void* d_ws, size_t ws_size,
                              hipStream_t stream)
{
  const float* hidden  = (const float*)d_in[0];
  const float* Wqkv    = (const float*)d_in[1];
  const float* q_ln_w  = (const float*)d_in[2];
  const float* q_ln_b  = (const float*)d_in[3];
  const float* k_ln_w  = (const float*)d_in[4];
  const float* k_ln_b  = (const float*)d_in[5];
  const float* out_w   = (const float*)d_in[6];
  const float* k_cache = (const float*)d_in[7];
  const float* v_cache = (const float*)d_in[8];
  const int*   cache_idx = (const int*)d_in[9];
  const int*   Sk        = (const int*)d_in[10];
  // d_in[11] = layernums (2 -> blend branch always taken)

  char* ws = (char*)d_ws;
  const size_t SZ_QKV = (size_t)T_TOK * D3 * 2;          // 24 MiB (bf16)
  const size_t SZ_TD  = (size_t)T_TOK * DM * 2;          //  8 MiB (bf16)
  bf16_t* qkv_bf  = (bf16_t*)ws;                         // [0, 24M)
  bf16_t* k_fin   = (bf16_t*)(ws + SZ_QKV);              // [24M, 32M)
  bf16_t* v_fin   = (bf16_t*)(ws + SZ_QKV + SZ_TD);      // [32M, 40M)
  bf16_t* attn_bf = (bf16_t*)(ws + SZ_QKV + 2 * SZ_TD);  // [40M, 48M)

  // 1. QKV projection + clip (fp32 inputs converted in staging) -> qkv_bf
  gemm_bt_kernel<<<dim3(D3 / 128, T_TOK / 128), 256, 0, stream>>>(
      hidden, Wqkv, qkv_bf, T_TOK, D3, DM, 1, 1, 0, 1);

  // 2. LN(q), LN(k) in place; gather k_fin/v_fin
  ln_gather_kernel<<<dim3(T_TOK), 256, 0, stream>>>(
      qkv_bf, q_ln_w, q_ln_b, k_ln_w, k_ln_b, k_cache, v_cache, cache_idx,
      k_fin, v_fin);

  // 3. Sk alpha blend
  sk_blend_kernel<<<dim3(in_sizes[10]), 256, 0, stream>>>(
      Sk, cache_idx, k_cache, v_cache, qkv_bf, k_fin, v_fin);

  // 4. BISECT: reference-style vector attention -> attn_bf
  attn_ref_kernel<<<dim3(T_TOK, NHEAD), 256, 0, stream>>>(
      qkv_bf, k_fin, v_fin, attn_bf);

  // 5. output projection -> d_out (fp32)
  gemm_bt_kernel<<<dim3(DM / 128, T_TOK / 128), 256, 0, stream>>>(
      attn_bf, out_w, d_out, T_TOK, DM, DM, 0, 1, 1, 0);
}